// Round 11
// baseline (366.572 us; speedup 1.0000x reference)
//
#include <hip/hip_runtime.h>
#include <math.h>

#define NB     32768
#define TT     1024
#define BBATCH 32
#define WPB    8      // waves per k_main block
#define SPW    8      // samples per wave

// ws layout:
// [0,512)     stats1 double[64]
// [512,2560)  stats2 double[256]
// [4096, +16MB)           z float[NB*128]
// [4096+16MB, +48MB)      hout float[NB*384]  (reused as fpart after k_conv)
#define Z_OFF    4096
#define HOUT_OFF (4096 + (size_t)NB * 128 * 4)

__global__ __launch_bounds__(256) void k_stats1(
    const float* __restrict__ x, const float* __restrict__ adj,
    const float* __restrict__ W0, const float* __restrict__ b0,
    double* __restrict__ stats1)
{
    __shared__ float adjL[144];
    __shared__ double redS[256], redQ[256];
    int tid = threadIdx.x;
    for (int i = tid; i < 144; i += 256) adjL[i] = adj[i];
    __syncthreads();
    int f = tid & 31, slot = tid >> 5;
    float w0a = W0[f], w0b = W0[32 + f], b0f = b0[f];
    double aS = 0.0, aQ = 0.0;
    for (int s = blockIdx.x * 8 + slot; s < NB; s += gridDim.x * 8) {
        const float* xp = x + (size_t)s * 24;
        float t0[12];
#pragma unroll
        for (int m = 0; m < 12; m++) t0[m] = xp[m * 2] * w0a + xp[m * 2 + 1] * w0b;
#pragma unroll
        for (int n = 0; n < 12; n++) {
            float y = b0f;
#pragma unroll
            for (int m = 0; m < 12; m++) y += adjL[n * 12 + m] * t0[m];
            aS += y; aQ += (double)y * y;
        }
    }
    redS[tid] = aS; redQ[tid] = aQ;
    __syncthreads();
    if (tid < 32) {
        for (int sl = 1; sl < 8; sl++) { aS += redS[sl * 32 + tid]; aQ += redQ[sl * 32 + tid]; }
        atomicAdd(&stats1[tid], aS);
        atomicAdd(&stats1[32 + tid], aQ);
    }
}

// ---- k_main: wave-per-sample, GAT double-refold, fused output GEMM --------
// (FROZEN from R10: VGPR 108, no spill, 183 us, VALUBusy ~64%)
__global__ __launch_bounds__(512, 2) void k_main(
    const float* __restrict__ x, const float* __restrict__ adj,
    const float* __restrict__ W0, const float* __restrict__ b0,
    const float* __restrict__ W1, const float* __restrict__ b1,
    const float* __restrict__ Wr, const float* __restrict__ br,
    const float* __restrict__ g_bn, const float* __restrict__ be_bn,
    const float* __restrict__ Watt, const float* __restrict__ a_l,
    const float* __restrict__ a_r, const float* __restrict__ Wmh,
    const double* __restrict__ stats1, float* __restrict__ houtG)
{
    __shared__ __align__(16) float adjL[192];      // [12][16]
    __shared__ __align__(16) float W1T[1152];      // [f 32][k 36]
    __shared__ __align__(16) float vaL[288];       // [type*4+h][36]
    __shared__ __align__(16) float Wmh0T[1152];    // [f 32][k 36]
    __shared__ __align__(16) float WfoldT[4608];   // [h 4][f 32][k 36]
    __shared__ __align__(16) float S[9216];

    const int tid = threadIdx.x;
    if (tid < 144) adjL[(tid / 12) * 16 + (tid % 12)] = adj[tid];
    for (int i = tid; i < 1024; i += 512) W1T[(i & 31) * 36 + (i >> 5)] = W1[i];
    for (int i = tid; i < 4096; i += 512) S[i] = Watt[i];
    for (int i = tid; i < 5120; i += 512) S[4096 + i] = Wmh[i];
    __syncthreads();
    for (int i = tid; i < 1024; i += 512)
        Wmh0T[(i & 31) * 36 + (i >> 5)] = S[4096 + i];
    if (tid < 256) {
        int type = tid >> 7, h = (tid >> 5) & 3, k = tid & 31;
        const float* av = type ? a_r : a_l;
        float acc = 0.f;
        for (int o = 0; o < 32; o++) acc += S[h * 1024 + k * 32 + o] * av[h * 32 + o];
        vaL[(type * 4 + h) * 36 + k] = acc;
    }
    for (int t = tid; t < 4096; t += 512) {
        int h = t >> 10, k = (t >> 5) & 31, f = t & 31;
        float acc = 0.f;
        for (int o = 0; o < 32; o++)
            acc += S[h * 1024 + k * 32 + o] * S[4096 + (32 + h * 32 + o) * 32 + f];
        WfoldT[h * 1152 + f * 36 + k] = acc;
    }
    __syncthreads();

    const int lane = tid & 63;
    const int wv = tid >> 6;
    const int f = lane & 31;
    const int p = lane >> 5;
    float* hbuf = &S[wv * 1120];
    float* eW   = &S[wv * 1120 + 432];
    float* attW = &S[wv * 1120 + 544];

    const float W0c0 = W0[f], W0c1 = W0[32 + f];
    const float Wrc0 = Wr[f], Wrc1 = Wr[32 + f];
    const float brc = br[f], b0c = b0[f], b1c = b1[f];
    double cnt = (double)NB * 12.0;
    double m1 = stats1[f] / cnt;
    double v1 = stats1[32 + f] / cnt - m1 * m1;
    const float sc1 = (float)((double)g_bn[f] / sqrt(v1 + 1e-5));
    const float sh1 = be_bn[f] - (float)m1 * sc1;

    const int base = (blockIdx.x * WPB + wv) * SPW;

#pragma unroll 1
    for (int si = 0; si < SPW; si++) {
        const int s = base + si;
        float2 xv[6];
#pragma unroll
        for (int j = 0; j < 6; j++)
            xv[j] = *(const float2*)&x[(size_t)s * 24 + (p + 2 * j) * 2];

        float t0[6], res[6];
#pragma unroll
        for (int j = 0; j < 6; j++) {
            t0[j]  = xv[j].x * W0c0 + xv[j].y * W0c1;
            res[j] = xv[j].x * Wrc0 + xv[j].y * Wrc1 + brc;
        }
        float t0all[12];
#pragma unroll
        for (int j = 0; j < 6; j++) {
            float o = __shfl_xor(t0[j], 32);
            t0all[2 * j]     = p ? o : t0[j];
            t0all[2 * j + 1] = p ? t0[j] : o;
        }
#pragma unroll
        for (int j = 0; j < 6; j++) {
            const float* arow = &adjL[(p + 2 * j) * 16];
            float acc = b0c;
#pragma unroll
            for (int m4 = 0; m4 < 3; m4++) {
                float4 a4 = *(const float4*)&arow[m4 * 4];
                acc += a4.x * t0all[m4 * 4] + a4.y * t0all[m4 * 4 + 1]
                     + a4.z * t0all[m4 * 4 + 2] + a4.w * t0all[m4 * 4 + 3];
            }
            hbuf[(p + 2 * j) * 36 + f] = fmaxf(acc * sc1 + sh1, 0.f);
        }
        float t1[6] = {0.f, 0.f, 0.f, 0.f, 0.f, 0.f};
#pragma unroll
        for (int k4 = 0; k4 < 8; k4++) {
            float4 w4 = *(const float4*)&W1T[f * 36 + k4 * 4];
#pragma unroll
            for (int j = 0; j < 6; j++) {
                float4 v = *(const float4*)&hbuf[(p + 2 * j) * 36 + k4 * 4];
                t1[j] += v.x * w4.x + v.y * w4.y + v.z * w4.z + v.w * w4.w;
            }
        }
        float t1all[12];
#pragma unroll
        for (int j = 0; j < 6; j++) {
            float o = __shfl_xor(t1[j], 32);
            t1all[2 * j]     = p ? o : t1[j];
            t1all[2 * j + 1] = p ? t1[j] : o;
        }
#pragma unroll
        for (int j = 0; j < 6; j++) {
            const float* arow = &adjL[(p + 2 * j) * 16];
            float acc = b1c;
#pragma unroll
            for (int m4 = 0; m4 < 3; m4++) {
                float4 a4 = *(const float4*)&arow[m4 * 4];
                acc += a4.x * t1all[m4 * 4] + a4.y * t1all[m4 * 4 + 1]
                     + a4.z * t1all[m4 * 4 + 2] + a4.w * t1all[m4 * 4 + 3];
            }
            hbuf[(p + 2 * j) * 36 + f] = acc + res[j];
        }

        {
            int t = lane;
            int ty = t / 48, rr = t % 48, hh = rr / 12, nn = rr % 12;
            float acc = 0.f;
#pragma unroll
            for (int k4 = 0; k4 < 8; k4++) {
                float4 hv = *(const float4*)&hbuf[nn * 36 + k4 * 4];
                float4 vv = *(const float4*)&vaL[(ty * 4 + hh) * 36 + k4 * 4];
                acc += hv.x * vv.x + hv.y * vv.y + hv.z * vv.z + hv.w * vv.w;
            }
            eW[ty ? (48 + hh * 16 + nn) : (hh * 12 + nn)] = acc;
        }
        if (lane < 32) {
            int rr = 16 + lane, hh = rr / 12, nn = rr % 12;
            float acc = 0.f;
#pragma unroll
            for (int k4 = 0; k4 < 8; k4++) {
                float4 hv = *(const float4*)&hbuf[nn * 36 + k4 * 4];
                float4 vv = *(const float4*)&vaL[(4 + hh) * 36 + k4 * 4];
                acc += hv.x * vv.x + hv.y * vv.y + hv.z * vv.z + hv.w * vv.w;
            }
            eW[48 + hh * 16 + nn] = acc;
        }
        if (lane < 48) {
            int hh = lane / 12;
            float el = eW[hh * 12 + (lane % 12)];
            float ev[12];
            float mx = -1e30f;
#pragma unroll
            for (int m4 = 0; m4 < 3; m4++) {
                float4 er4 = *(const float4*)&eW[48 + hh * 16 + m4 * 4];
                float e0 = el + er4.x; e0 = e0 > 0.f ? e0 : 0.01f * e0;
                float e1 = el + er4.y; e1 = e1 > 0.f ? e1 : 0.01f * e1;
                float e2 = el + er4.z; e2 = e2 > 0.f ? e2 : 0.01f * e2;
                float e3 = el + er4.w; e3 = e3 > 0.f ? e3 : 0.01f * e3;
                ev[m4 * 4] = e0; ev[m4 * 4 + 1] = e1; ev[m4 * 4 + 2] = e2; ev[m4 * 4 + 3] = e3;
                mx = fmaxf(mx, fmaxf(fmaxf(e0, e1), fmaxf(e2, e3)));
            }
            float sum = 0.f;
#pragma unroll
            for (int m = 0; m < 12; m++) { float e = __expf(ev[m] - mx); ev[m] = e; sum += e; }
            float inv = 1.f / sum;
#pragma unroll
            for (int m4 = 0; m4 < 3; m4++) {
                float4 o;
                o.x = ev[m4 * 4] * inv; o.y = ev[m4 * 4 + 1] * inv;
                o.z = ev[m4 * 4 + 2] * inv; o.w = ev[m4 * 4 + 3] * inv;
                *(float4*)&attW[lane * 12 + m4 * 4] = o;
            }
        }

        float ho[6] = {0.f, 0.f, 0.f, 0.f, 0.f, 0.f};
        float q0[6] = {0.f, 0.f, 0.f, 0.f, 0.f, 0.f};
        float q1[6] = {0.f, 0.f, 0.f, 0.f, 0.f, 0.f};
        float q2[6] = {0.f, 0.f, 0.f, 0.f, 0.f, 0.f};
        float q3[6] = {0.f, 0.f, 0.f, 0.f, 0.f, 0.f};
#pragma unroll 2
        for (int k4 = 0; k4 < 8; k4++) {
            float4 v[6];
#pragma unroll
            for (int j = 0; j < 6; j++)
                v[j] = *(const float4*)&hbuf[(p + 2 * j) * 36 + k4 * 4];
            float4 wm = *(const float4*)&Wmh0T[f * 36 + k4 * 4];
#pragma unroll
            for (int j = 0; j < 6; j++)
                ho[j] += v[j].x * wm.x + v[j].y * wm.y + v[j].z * wm.z + v[j].w * wm.w;
            float4 wh0 = *(const float4*)&WfoldT[0 * 1152 + f * 36 + k4 * 4];
            float4 wh1 = *(const float4*)&WfoldT[1 * 1152 + f * 36 + k4 * 4];
            float4 wh2 = *(const float4*)&WfoldT[2 * 1152 + f * 36 + k4 * 4];
            float4 wh3 = *(const float4*)&WfoldT[3 * 1152 + f * 36 + k4 * 4];
#pragma unroll
            for (int j = 0; j < 6; j++) {
                q0[j] += v[j].x * wh0.x + v[j].y * wh0.y + v[j].z * wh0.z + v[j].w * wh0.w;
                q1[j] += v[j].x * wh1.x + v[j].y * wh1.y + v[j].z * wh1.z + v[j].w * wh1.w;
                q2[j] += v[j].x * wh2.x + v[j].y * wh2.y + v[j].z * wh2.z + v[j].w * wh2.w;
                q3[j] += v[j].x * wh3.x + v[j].y * wh3.y + v[j].z * wh3.z + v[j].w * wh3.w;
            }
        }
#pragma unroll
        for (int h = 0; h < 4; h++) {
            float qall[12];
#pragma unroll
            for (int j = 0; j < 6; j++) {
                float qo = (h == 0) ? q0[j] : (h == 1) ? q1[j] : (h == 2) ? q2[j] : q3[j];
                float o = __shfl_xor(qo, 32);
                qall[2 * j]     = p ? o : qo;
                qall[2 * j + 1] = p ? qo : o;
            }
#pragma unroll
            for (int j = 0; j < 6; j++) {
                const float* arow = &attW[(h * 12 + (p + 2 * j)) * 12];
                float4 a0 = *(const float4*)&arow[0];
                float4 a1 = *(const float4*)&arow[4];
                float4 a2 = *(const float4*)&arow[8];
                ho[j] += a0.x * qall[0] + a0.y * qall[1] + a0.z * qall[2] + a0.w * qall[3]
                       + a1.x * qall[4] + a1.y * qall[5] + a1.z * qall[6] + a1.w * qall[7]
                       + a2.x * qall[8] + a2.y * qall[9] + a2.z * qall[10] + a2.w * qall[11];
            }
        }
#pragma unroll
        for (int j = 0; j < 6; j++)
            houtG[(size_t)s * 384 + (p + 2 * j) * 32 + f] = ho[j];
    }
}

// ---- k_conv: z = hout[NB,384] @ Wc^T, 64x128 tile, acc[4][8], 256 thr -----
// R10 analysis: acc[2][8] was DS-bound (10 ds_read_b128 per 16 FMA4).
// acc[4][8] -> 12 reads per 32 FMA4 (1.7x better FMA:DS ratio).
__global__ __launch_bounds__(256, 2) void k_conv(
    const float* __restrict__ hout, const float* __restrict__ Wc,
    float* __restrict__ z, double* __restrict__ stats2)
{
    __shared__ __align__(16) float sA[64 * 36];    // samples x k
    __shared__ __align__(16) float sB[128 * 36];   // channels x k
    const int tid = threadIdx.x;
    const int s0 = blockIdx.x * 64;
    const int tx = tid & 15;     // ch = tx + 16j
    const int ty = tid >> 4;     // 0..15; sample rows ty + 16i
    float acc[4][8];
#pragma unroll
    for (int i = 0; i < 4; i++)
#pragma unroll
        for (int j = 0; j < 8; j++) acc[i][j] = 0.f;

#pragma unroll 1
    for (int kc = 0; kc < 12; kc++) {
        const int k0 = kc * 32;
        {
            int ra = tid >> 2, qa = tid & 3;   // A: 64 rows x 4 groups of 8
            const float* ga = &hout[(size_t)(s0 + ra) * 384 + k0 + qa * 8];
            float4 v0 = *(const float4*)&ga[0];
            float4 v1 = *(const float4*)&ga[4];
            *(float4*)&sA[ra * 36 + qa * 8]     = v0;
            *(float4*)&sA[ra * 36 + qa * 8 + 4] = v1;
            int rb = tid >> 1, qb = tid & 1;   // B: 128 rows x 2 groups of 16
            const float* gb = &Wc[(size_t)rb * 384 + k0 + qb * 16];
            float4 w0 = *(const float4*)&gb[0];
            float4 w1 = *(const float4*)&gb[4];
            float4 w2 = *(const float4*)&gb[8];
            float4 w3 = *(const float4*)&gb[12];
            *(float4*)&sB[rb * 36 + qb * 16]      = w0;
            *(float4*)&sB[rb * 36 + qb * 16 + 4]  = w1;
            *(float4*)&sB[rb * 36 + qb * 16 + 8]  = w2;
            *(float4*)&sB[rb * 36 + qb * 16 + 12] = w3;
        }
        __syncthreads();
#pragma unroll
        for (int k4 = 0; k4 < 8; k4++) {
            float4 av[4], bv[8];
#pragma unroll
            for (int i = 0; i < 4; i++) av[i] = *(const float4*)&sA[(ty + 16 * i) * 36 + k4 * 4];
#pragma unroll
            for (int j = 0; j < 8; j++) bv[j] = *(const float4*)&sB[(tx + 16 * j) * 36 + k4 * 4];
#pragma unroll
            for (int i = 0; i < 4; i++)
#pragma unroll
                for (int j = 0; j < 8; j++)
                    acc[i][j] += av[i].x * bv[j].x + av[i].y * bv[j].y
                               + av[i].z * bv[j].z + av[i].w * bv[j].w;
        }
        __syncthreads();
    }
#pragma unroll
    for (int i = 0; i < 4; i++)
#pragma unroll
        for (int j = 0; j < 8; j++)
            z[(size_t)(s0 + ty + 16 * i) * 128 + tx + 16 * j] = acc[i][j];

    // fused stats2: lanes l, l+16, l+32, l+48 share tx -> shfl reduce
    const int lane = tid & 63, wv = tid >> 6;   // 4 waves
    float s1[8], s2[8];
#pragma unroll
    for (int j = 0; j < 8; j++) {
        float a0 = acc[0][j], a1 = acc[1][j], a2 = acc[2][j], a3 = acc[3][j];
        float v1 = a0 + a1 + a2 + a3;
        float v2 = a0 * a0 + a1 * a1 + a2 * a2 + a3 * a3;
        v1 += __shfl_down(v1, 32); v1 += __shfl_down(v1, 16);
        v2 += __shfl_down(v2, 32); v2 += __shfl_down(v2, 16);
        s1[j] = v1; s2[j] = v2;
    }
    if (lane < 16) {
#pragma unroll
        for (int j = 0; j < 8; j++) {
            sA[wv * 128 + lane + 16 * j] = s1[j];
            sB[wv * 128 + lane + 16 * j] = s2[j];
        }
    }
    __syncthreads();
    if (tid < 128) {
        float aS = 0.f, aQ = 0.f;
#pragma unroll
        for (int r = 0; r < 4; r++) { aS += sA[r * 128 + tid]; aQ += sB[r * 128 + tid]; }
        atomicAdd(&stats2[tid], (double)aS);
        atomicAdd(&stats2[128 + tid], (double)aQ);
    }
}

__global__ __launch_bounds__(128) void k_final_part(
    const float* __restrict__ z, const double* __restrict__ stats2,
    const float* __restrict__ g2, const float* __restrict__ be2,
    float* __restrict__ fpart)
{
    int ch = threadIdx.x;
    int b = blockIdx.x >> 5, c = blockIdx.x & 31;
    double cnt = (double)NB;
    double m = stats2[ch] / cnt;
    double var = stats2[128 + ch] / cnt - m * m;
    float mean = (float)m, rstd = (float)(1.0 / sqrt(var + 1e-5));
    float g = g2[ch], be = be2[ch];
    const float* zp = z + ((size_t)b * TT + c * 32) * 128 + ch;
    float acc = 0.f;
    for (int t = 0; t < 32; t++) {
        float v = zp[t * 128];
        v = (v - mean) * rstd * g + be;
        acc += fmaxf(v, 0.f);
    }
    fpart[(size_t)blockIdx.x * 128 + ch] = acc;
}

__global__ __launch_bounds__(128) void k_final2(
    const float* __restrict__ fpart,
    const float* __restrict__ Wl, const float* __restrict__ bl,
    float* __restrict__ out)
{
    __shared__ float poolL[128];
    int ch = threadIdx.x, b = blockIdx.x;
    float acc = 0.f;
    for (int c = 0; c < 32; c++) acc += fpart[(size_t)(b * 32 + c) * 128 + ch];
    poolL[ch] = acc * (1.0f / TT);
    __syncthreads();
    if (ch < 10) {
        float o = bl[ch];
        for (int c = 0; c < 128; c++) o += poolL[c] * Wl[c * 10 + ch];
        out[b * 10 + ch] = o;
    }
}

extern "C" void kernel_launch(void* const* d_in, const int* in_sizes, int n_in,
                              void* d_out, int out_size, void* d_ws, size_t ws_size,
                              hipStream_t stream)
{
    const float* x    = (const float*)d_in[0];
    const float* adj  = (const float*)d_in[1];
    const float* W0   = (const float*)d_in[2];
    const float* b0   = (const float*)d_in[3];
    const float* W1   = (const float*)d_in[4];
    const float* b1   = (const float*)d_in[5];
    const float* Wr   = (const float*)d_in[6];
    const float* br   = (const float*)d_in[7];
    const float* gbn  = (const float*)d_in[8];
    const float* bebn = (const float*)d_in[9];
    const float* Watt = (const float*)d_in[10];
    const float* al   = (const float*)d_in[11];
    const float* ar   = (const float*)d_in[12];
    const float* Wmh  = (const float*)d_in[13];
    const float* Wc   = (const float*)d_in[14];
    const float* g2   = (const float*)d_in[15];
    const float* be2  = (const float*)d_in[16];
    const float* Wl   = (const float*)d_in[17];
    const float* bl   = (const float*)d_in[18];
    float* out = (float*)d_out;

    double* stats1 = (double*)d_ws;
    double* stats2 = (double*)((char*)d_ws + 512);
    float*  z      = (float*)((char*)d_ws + Z_OFF);
    float*  houtG  = (float*)((char*)d_ws + HOUT_OFF);
    float*  fpart  = houtG;

    hipMemsetAsync(d_ws, 0, 4096, stream);
    k_stats1<<<512, 256, 0, stream>>>(x, adj, W0, b0, stats1);
    k_main<<<NB / (WPB * SPW), 512, 0, stream>>>(x, adj, W0, b0, W1, b1, Wr, br,
                                                 gbn, bebn, Watt, al, ar, Wmh,
                                                 stats1, houtG);
    k_conv<<<NB / 64, 256, 0, stream>>>(houtG, Wc, z, stats2);
    k_final_part<<<BBATCH * 32, 128, 0, stream>>>(z, stats2, g2, be2, fpart);
    k_final2<<<BBATCH, 128, 0, stream>>>(fpart, Wl, bl, out);
}

// Round 12
// 277.094 us; speedup vs baseline: 1.3229x; 1.3229x over previous
//
#include <hip/hip_runtime.h>
#include <math.h>

#define NB     32768
#define TT     1024
#define BBATCH 32
#define WPB    8      // waves per k_main block
#define SPW    8      // samples per wave

// ws layout:
// [0,512)     stats1 double[64]
// [512,2560)  stats2 double[256]
// [4096, +16MB)           z float[NB*128]
// [4096+16MB, +48MB)      hout float[NB*384]  (reused as fpart after k_conv)
#define Z_OFF    4096
#define HOUT_OFF (4096 + (size_t)NB * 128 * 4)

__global__ __launch_bounds__(256) void k_stats1(
    const float* __restrict__ x, const float* __restrict__ adj,
    const float* __restrict__ W0, const float* __restrict__ b0,
    double* __restrict__ stats1)
{
    __shared__ float adjL[144];
    __shared__ double redS[256], redQ[256];
    int tid = threadIdx.x;
    for (int i = tid; i < 144; i += 256) adjL[i] = adj[i];
    __syncthreads();
    int f = tid & 31, slot = tid >> 5;
    float w0a = W0[f], w0b = W0[32 + f], b0f = b0[f];
    double aS = 0.0, aQ = 0.0;
    for (int s = blockIdx.x * 8 + slot; s < NB; s += gridDim.x * 8) {
        const float* xp = x + (size_t)s * 24;
        float t0[12];
#pragma unroll
        for (int m = 0; m < 12; m++) t0[m] = xp[m * 2] * w0a + xp[m * 2 + 1] * w0b;
#pragma unroll
        for (int n = 0; n < 12; n++) {
            float y = b0f;
#pragma unroll
            for (int m = 0; m < 12; m++) y += adjL[n * 12 + m] * t0[m];
            aS += y; aQ += (double)y * y;
        }
    }
    redS[tid] = aS; redQ[tid] = aQ;
    __syncthreads();
    if (tid < 32) {
        for (int sl = 1; sl < 8; sl++) { aS += redS[sl * 32 + tid]; aQ += redQ[sl * 32 + tid]; }
        atomicAdd(&stats1[tid], aS);
        atomicAdd(&stats1[32 + tid], aQ);
    }
}

// ---- k_main: wave-per-sample, GAT double-refold, fused output GEMM --------
// (FROZEN from R10: VGPR 108, no spill, 183 us, VALUBusy ~64%)
__global__ __launch_bounds__(512, 2) void k_main(
    const float* __restrict__ x, const float* __restrict__ adj,
    const float* __restrict__ W0, const float* __restrict__ b0,
    const float* __restrict__ W1, const float* __restrict__ b1,
    const float* __restrict__ Wr, const float* __restrict__ br,
    const float* __restrict__ g_bn, const float* __restrict__ be_bn,
    const float* __restrict__ Watt, const float* __restrict__ a_l,
    const float* __restrict__ a_r, const float* __restrict__ Wmh,
    const double* __restrict__ stats1, float* __restrict__ houtG)
{
    __shared__ __align__(16) float adjL[192];      // [12][16]
    __shared__ __align__(16) float W1T[1152];      // [f 32][k 36]
    __shared__ __align__(16) float vaL[288];       // [type*4+h][36]
    __shared__ __align__(16) float Wmh0T[1152];    // [f 32][k 36]
    __shared__ __align__(16) float WfoldT[4608];   // [h 4][f 32][k 36]
    __shared__ __align__(16) float S[9216];

    const int tid = threadIdx.x;
    if (tid < 144) adjL[(tid / 12) * 16 + (tid % 12)] = adj[tid];
    for (int i = tid; i < 1024; i += 512) W1T[(i & 31) * 36 + (i >> 5)] = W1[i];
    for (int i = tid; i < 4096; i += 512) S[i] = Watt[i];
    for (int i = tid; i < 5120; i += 512) S[4096 + i] = Wmh[i];
    __syncthreads();
    for (int i = tid; i < 1024; i += 512)
        Wmh0T[(i & 31) * 36 + (i >> 5)] = S[4096 + i];
    if (tid < 256) {
        int type = tid >> 7, h = (tid >> 5) & 3, k = tid & 31;
        const float* av = type ? a_r : a_l;
        float acc = 0.f;
        for (int o = 0; o < 32; o++) acc += S[h * 1024 + k * 32 + o] * av[h * 32 + o];
        vaL[(type * 4 + h) * 36 + k] = acc;
    }
    for (int t = tid; t < 4096; t += 512) {
        int h = t >> 10, k = (t >> 5) & 31, f = t & 31;
        float acc = 0.f;
        for (int o = 0; o < 32; o++)
            acc += S[h * 1024 + k * 32 + o] * S[4096 + (32 + h * 32 + o) * 32 + f];
        WfoldT[h * 1152 + f * 36 + k] = acc;
    }
    __syncthreads();

    const int lane = tid & 63;
    const int wv = tid >> 6;
    const int f = lane & 31;
    const int p = lane >> 5;
    float* hbuf = &S[wv * 1120];
    float* eW   = &S[wv * 1120 + 432];
    float* attW = &S[wv * 1120 + 544];

    const float W0c0 = W0[f], W0c1 = W0[32 + f];
    const float Wrc0 = Wr[f], Wrc1 = Wr[32 + f];
    const float brc = br[f], b0c = b0[f], b1c = b1[f];
    double cnt = (double)NB * 12.0;
    double m1 = stats1[f] / cnt;
    double v1 = stats1[32 + f] / cnt - m1 * m1;
    const float sc1 = (float)((double)g_bn[f] / sqrt(v1 + 1e-5));
    const float sh1 = be_bn[f] - (float)m1 * sc1;

    const int base = (blockIdx.x * WPB + wv) * SPW;

#pragma unroll 1
    for (int si = 0; si < SPW; si++) {
        const int s = base + si;
        float2 xv[6];
#pragma unroll
        for (int j = 0; j < 6; j++)
            xv[j] = *(const float2*)&x[(size_t)s * 24 + (p + 2 * j) * 2];

        float t0[6], res[6];
#pragma unroll
        for (int j = 0; j < 6; j++) {
            t0[j]  = xv[j].x * W0c0 + xv[j].y * W0c1;
            res[j] = xv[j].x * Wrc0 + xv[j].y * Wrc1 + brc;
        }
        float t0all[12];
#pragma unroll
        for (int j = 0; j < 6; j++) {
            float o = __shfl_xor(t0[j], 32);
            t0all[2 * j]     = p ? o : t0[j];
            t0all[2 * j + 1] = p ? t0[j] : o;
        }
#pragma unroll
        for (int j = 0; j < 6; j++) {
            const float* arow = &adjL[(p + 2 * j) * 16];
            float acc = b0c;
#pragma unroll
            for (int m4 = 0; m4 < 3; m4++) {
                float4 a4 = *(const float4*)&arow[m4 * 4];
                acc += a4.x * t0all[m4 * 4] + a4.y * t0all[m4 * 4 + 1]
                     + a4.z * t0all[m4 * 4 + 2] + a4.w * t0all[m4 * 4 + 3];
            }
            hbuf[(p + 2 * j) * 36 + f] = fmaxf(acc * sc1 + sh1, 0.f);
        }
        float t1[6] = {0.f, 0.f, 0.f, 0.f, 0.f, 0.f};
#pragma unroll
        for (int k4 = 0; k4 < 8; k4++) {
            float4 w4 = *(const float4*)&W1T[f * 36 + k4 * 4];
#pragma unroll
            for (int j = 0; j < 6; j++) {
                float4 v = *(const float4*)&hbuf[(p + 2 * j) * 36 + k4 * 4];
                t1[j] += v.x * w4.x + v.y * w4.y + v.z * w4.z + v.w * w4.w;
            }
        }
        float t1all[12];
#pragma unroll
        for (int j = 0; j < 6; j++) {
            float o = __shfl_xor(t1[j], 32);
            t1all[2 * j]     = p ? o : t1[j];
            t1all[2 * j + 1] = p ? t1[j] : o;
        }
#pragma unroll
        for (int j = 0; j < 6; j++) {
            const float* arow = &adjL[(p + 2 * j) * 16];
            float acc = b1c;
#pragma unroll
            for (int m4 = 0; m4 < 3; m4++) {
                float4 a4 = *(const float4*)&arow[m4 * 4];
                acc += a4.x * t1all[m4 * 4] + a4.y * t1all[m4 * 4 + 1]
                     + a4.z * t1all[m4 * 4 + 2] + a4.w * t1all[m4 * 4 + 3];
            }
            hbuf[(p + 2 * j) * 36 + f] = acc + res[j];
        }

        {
            int t = lane;
            int ty = t / 48, rr = t % 48, hh = rr / 12, nn = rr % 12;
            float acc = 0.f;
#pragma unroll
            for (int k4 = 0; k4 < 8; k4++) {
                float4 hv = *(const float4*)&hbuf[nn * 36 + k4 * 4];
                float4 vv = *(const float4*)&vaL[(ty * 4 + hh) * 36 + k4 * 4];
                acc += hv.x * vv.x + hv.y * vv.y + hv.z * vv.z + hv.w * vv.w;
            }
            eW[ty ? (48 + hh * 16 + nn) : (hh * 12 + nn)] = acc;
        }
        if (lane < 32) {
            int rr = 16 + lane, hh = rr / 12, nn = rr % 12;
            float acc = 0.f;
#pragma unroll
            for (int k4 = 0; k4 < 8; k4++) {
                float4 hv = *(const float4*)&hbuf[nn * 36 + k4 * 4];
                float4 vv = *(const float4*)&vaL[(4 + hh) * 36 + k4 * 4];
                acc += hv.x * vv.x + hv.y * vv.y + hv.z * vv.z + hv.w * vv.w;
            }
            eW[48 + hh * 16 + nn] = acc;
        }
        if (lane < 48) {
            int hh = lane / 12;
            float el = eW[hh * 12 + (lane % 12)];
            float ev[12];
            float mx = -1e30f;
#pragma unroll
            for (int m4 = 0; m4 < 3; m4++) {
                float4 er4 = *(const float4*)&eW[48 + hh * 16 + m4 * 4];
                float e0 = el + er4.x; e0 = e0 > 0.f ? e0 : 0.01f * e0;
                float e1 = el + er4.y; e1 = e1 > 0.f ? e1 : 0.01f * e1;
                float e2 = el + er4.z; e2 = e2 > 0.f ? e2 : 0.01f * e2;
                float e3 = el + er4.w; e3 = e3 > 0.f ? e3 : 0.01f * e3;
                ev[m4 * 4] = e0; ev[m4 * 4 + 1] = e1; ev[m4 * 4 + 2] = e2; ev[m4 * 4 + 3] = e3;
                mx = fmaxf(mx, fmaxf(fmaxf(e0, e1), fmaxf(e2, e3)));
            }
            float sum = 0.f;
#pragma unroll
            for (int m = 0; m < 12; m++) { float e = __expf(ev[m] - mx); ev[m] = e; sum += e; }
            float inv = 1.f / sum;
#pragma unroll
            for (int m4 = 0; m4 < 3; m4++) {
                float4 o;
                o.x = ev[m4 * 4] * inv; o.y = ev[m4 * 4 + 1] * inv;
                o.z = ev[m4 * 4 + 2] * inv; o.w = ev[m4 * 4 + 3] * inv;
                *(float4*)&attW[lane * 12 + m4 * 4] = o;
            }
        }

        float ho[6] = {0.f, 0.f, 0.f, 0.f, 0.f, 0.f};
        float q0[6] = {0.f, 0.f, 0.f, 0.f, 0.f, 0.f};
        float q1[6] = {0.f, 0.f, 0.f, 0.f, 0.f, 0.f};
        float q2[6] = {0.f, 0.f, 0.f, 0.f, 0.f, 0.f};
        float q3[6] = {0.f, 0.f, 0.f, 0.f, 0.f, 0.f};
#pragma unroll 2
        for (int k4 = 0; k4 < 8; k4++) {
            float4 v[6];
#pragma unroll
            for (int j = 0; j < 6; j++)
                v[j] = *(const float4*)&hbuf[(p + 2 * j) * 36 + k4 * 4];
            float4 wm = *(const float4*)&Wmh0T[f * 36 + k4 * 4];
#pragma unroll
            for (int j = 0; j < 6; j++)
                ho[j] += v[j].x * wm.x + v[j].y * wm.y + v[j].z * wm.z + v[j].w * wm.w;
            float4 wh0 = *(const float4*)&WfoldT[0 * 1152 + f * 36 + k4 * 4];
            float4 wh1 = *(const float4*)&WfoldT[1 * 1152 + f * 36 + k4 * 4];
            float4 wh2 = *(const float4*)&WfoldT[2 * 1152 + f * 36 + k4 * 4];
            float4 wh3 = *(const float4*)&WfoldT[3 * 1152 + f * 36 + k4 * 4];
#pragma unroll
            for (int j = 0; j < 6; j++) {
                q0[j] += v[j].x * wh0.x + v[j].y * wh0.y + v[j].z * wh0.z + v[j].w * wh0.w;
                q1[j] += v[j].x * wh1.x + v[j].y * wh1.y + v[j].z * wh1.z + v[j].w * wh1.w;
                q2[j] += v[j].x * wh2.x + v[j].y * wh2.y + v[j].z * wh2.z + v[j].w * wh2.w;
                q3[j] += v[j].x * wh3.x + v[j].y * wh3.y + v[j].z * wh3.z + v[j].w * wh3.w;
            }
        }
#pragma unroll
        for (int h = 0; h < 4; h++) {
            float qall[12];
#pragma unroll
            for (int j = 0; j < 6; j++) {
                float qo = (h == 0) ? q0[j] : (h == 1) ? q1[j] : (h == 2) ? q2[j] : q3[j];
                float o = __shfl_xor(qo, 32);
                qall[2 * j]     = p ? o : qo;
                qall[2 * j + 1] = p ? qo : o;
            }
#pragma unroll
            for (int j = 0; j < 6; j++) {
                const float* arow = &attW[(h * 12 + (p + 2 * j)) * 12];
                float4 a0 = *(const float4*)&arow[0];
                float4 a1 = *(const float4*)&arow[4];
                float4 a2 = *(const float4*)&arow[8];
                ho[j] += a0.x * qall[0] + a0.y * qall[1] + a0.z * qall[2] + a0.w * qall[3]
                       + a1.x * qall[4] + a1.y * qall[5] + a1.z * qall[6] + a1.w * qall[7]
                       + a2.x * qall[8] + a2.y * qall[9] + a2.z * qall[10] + a2.w * qall[11];
            }
        }
#pragma unroll
        for (int j = 0; j < 6; j++)
            houtG[(size_t)s * 384 + (p + 2 * j) * 32 + f] = ho[j];
    }
}

// ---- k_conv: z = hout[NB,384] @ Wc^T, 64x128 tile, acc[4][4], 512 thr -----
// R11 lesson: acc[4][8]@256thr spilled (WRITE 450MB). acc[4][4]@512thr:
// 8 ds_read_b128 per 16 FMA4 (vs R10's 10) AND fewer live regs than R10
// (acc16+av16+bv16+stage12 ~= 75-90 < 128 cap). bv rows stride 36:
// (r*9)%32 bijective -> conflict-free.
__global__ __launch_bounds__(512, 2) void k_conv(
    const float* __restrict__ hout, const float* __restrict__ Wc,
    float* __restrict__ z, double* __restrict__ stats2)
{
    __shared__ __align__(16) float sA[64 * 36];    // samples x k
    __shared__ __align__(16) float sB[128 * 36];   // channels x k
    const int tid = threadIdx.x;
    const int s0 = blockIdx.x * 64;
    const int tx = tid & 31;     // ch = tx + 32j, j<4
    const int ty = tid >> 5;     // 0..15; sample rows ty + 16i, i<4
    float acc[4][4];
#pragma unroll
    for (int i = 0; i < 4; i++)
#pragma unroll
        for (int j = 0; j < 4; j++) acc[i][j] = 0.f;

#pragma unroll 1
    for (int kc = 0; kc < 12; kc++) {
        const int k0 = kc * 32;
        {
            int ra = tid >> 3, qa = tid & 7;   // A: 64 rows x 8 groups of 4
            float4 va = *(const float4*)&hout[(size_t)(s0 + ra) * 384 + k0 + qa * 4];
            *(float4*)&sA[ra * 36 + qa * 4] = va;
            int rb = tid >> 2, qb = tid & 3;   // B: 128 rows x 4 groups of 8
            const float* gb = &Wc[(size_t)rb * 384 + k0 + qb * 8];
            float4 w0 = *(const float4*)&gb[0];
            float4 w1 = *(const float4*)&gb[4];
            *(float4*)&sB[rb * 36 + qb * 8]     = w0;
            *(float4*)&sB[rb * 36 + qb * 8 + 4] = w1;
        }
        __syncthreads();
#pragma unroll
        for (int k4 = 0; k4 < 8; k4++) {
            float4 av[4], bv[4];
#pragma unroll
            for (int i = 0; i < 4; i++) av[i] = *(const float4*)&sA[(ty + 16 * i) * 36 + k4 * 4];
#pragma unroll
            for (int j = 0; j < 4; j++) bv[j] = *(const float4*)&sB[(tx + 32 * j) * 36 + k4 * 4];
#pragma unroll
            for (int i = 0; i < 4; i++)
#pragma unroll
                for (int j = 0; j < 4; j++)
                    acc[i][j] += av[i].x * bv[j].x + av[i].y * bv[j].y
                               + av[i].z * bv[j].z + av[i].w * bv[j].w;
        }
        __syncthreads();
    }
#pragma unroll
    for (int i = 0; i < 4; i++)
#pragma unroll
        for (int j = 0; j < 4; j++)
            z[(size_t)(s0 + ty + 16 * i) * 128 + tx + 32 * j] = acc[i][j];

    // fused stats2: lanes l and l+32 share tx -> shfl reduce over ty pair
    const int lane = tid & 63, wv = tid >> 6;   // 8 waves
    float s1[4], s2[4];
#pragma unroll
    for (int j = 0; j < 4; j++) {
        float a0 = acc[0][j], a1 = acc[1][j], a2 = acc[2][j], a3 = acc[3][j];
        float v1 = a0 + a1 + a2 + a3;
        float v2 = a0 * a0 + a1 * a1 + a2 * a2 + a3 * a3;
        v1 += __shfl_down(v1, 32);
        v2 += __shfl_down(v2, 32);
        s1[j] = v1; s2[j] = v2;
    }
    if (lane < 32) {
#pragma unroll
        for (int j = 0; j < 4; j++) {
            sA[wv * 128 + lane + 32 * j] = s1[j];
            sB[wv * 128 + lane + 32 * j] = s2[j];
        }
    }
    __syncthreads();
    if (tid < 128) {
        float aS = 0.f, aQ = 0.f;
#pragma unroll
        for (int r = 0; r < 8; r++) { aS += sA[r * 128 + tid]; aQ += sB[r * 128 + tid]; }
        atomicAdd(&stats2[tid], (double)aS);
        atomicAdd(&stats2[128 + tid], (double)aQ);
    }
}

__global__ __launch_bounds__(128) void k_final_part(
    const float* __restrict__ z, const double* __restrict__ stats2,
    const float* __restrict__ g2, const float* __restrict__ be2,
    float* __restrict__ fpart)
{
    int ch = threadIdx.x;
    int b = blockIdx.x >> 5, c = blockIdx.x & 31;
    double cnt = (double)NB;
    double m = stats2[ch] / cnt;
    double var = stats2[128 + ch] / cnt - m * m;
    float mean = (float)m, rstd = (float)(1.0 / sqrt(var + 1e-5));
    float g = g2[ch], be = be2[ch];
    const float* zp = z + ((size_t)b * TT + c * 32) * 128 + ch;
    float acc = 0.f;
    for (int t = 0; t < 32; t++) {
        float v = zp[t * 128];
        v = (v - mean) * rstd * g + be;
        acc += fmaxf(v, 0.f);
    }
    fpart[(size_t)blockIdx.x * 128 + ch] = acc;
}

__global__ __launch_bounds__(128) void k_final2(
    const float* __restrict__ fpart,
    const float* __restrict__ Wl, const float* __restrict__ bl,
    float* __restrict__ out)
{
    __shared__ float poolL[128];
    int ch = threadIdx.x, b = blockIdx.x;
    float acc = 0.f;
    for (int c = 0; c < 32; c++) acc += fpart[(size_t)(b * 32 + c) * 128 + ch];
    poolL[ch] = acc * (1.0f / TT);
    __syncthreads();
    if (ch < 10) {
        float o = bl[ch];
        for (int c = 0; c < 128; c++) o += poolL[c] * Wl[c * 10 + ch];
        out[b * 10 + ch] = o;
    }
}

extern "C" void kernel_launch(void* const* d_in, const int* in_sizes, int n_in,
                              void* d_out, int out_size, void* d_ws, size_t ws_size,
                              hipStream_t stream)
{
    const float* x    = (const float*)d_in[0];
    const float* adj  = (const float*)d_in[1];
    const float* W0   = (const float*)d_in[2];
    const float* b0   = (const float*)d_in[3];
    const float* W1   = (const float*)d_in[4];
    const float* b1   = (const float*)d_in[5];
    const float* Wr   = (const float*)d_in[6];
    const float* br   = (const float*)d_in[7];
    const float* gbn  = (const float*)d_in[8];
    const float* bebn = (const float*)d_in[9];
    const float* Watt = (const float*)d_in[10];
    const float* al   = (const float*)d_in[11];
    const float* ar   = (const float*)d_in[12];
    const float* Wmh  = (const float*)d_in[13];
    const float* Wc   = (const float*)d_in[14];
    const float* g2   = (const float*)d_in[15];
    const float* be2  = (const float*)d_in[16];
    const float* Wl   = (const float*)d_in[17];
    const float* bl   = (const float*)d_in[18];
    float* out = (float*)d_out;

    double* stats1 = (double*)d_ws;
    double* stats2 = (double*)((char*)d_ws + 512);
    float*  z      = (float*)((char*)d_ws + Z_OFF);
    float*  houtG  = (float*)((char*)d_ws + HOUT_OFF);
    float*  fpart  = houtG;

    hipMemsetAsync(d_ws, 0, 4096, stream);
    k_stats1<<<512, 256, 0, stream>>>(x, adj, W0, b0, stats1);
    k_main<<<NB / (WPB * SPW), 512, 0, stream>>>(x, adj, W0, b0, W1, b1, Wr, br,
                                                 gbn, bebn, Watt, al, ar, Wmh,
                                                 stats1, houtG);
    k_conv<<<NB / 64, 512, 0, stream>>>(houtG, Wc, z, stats2);
    k_final_part<<<BBATCH * 32, 128, 0, stream>>>(z, stats2, g2, be2, fpart);
    k_final2<<<BBATCH, 128, 0, stream>>>(fpart, Wl, bl, out);
}